// Round 6
// baseline (5398.590 us; speedup 1.0000x reference)
//
#include <hip/hip_runtime.h>
#include <math.h>
#include <stdint.h>

// Problem constants
static constexpr int B_ = 128;
static constexpr int T_ = 64;
static constexpr int E_ = 2048;
static constexpr int H_ = 1024;
static constexpr int R_ = 8;
static constexpr int H3_ = 3 * H_;  // 3072

typedef unsigned short u16;
typedef __attribute__((ext_vector_type(8))) __bf16 bf16x8;
typedef __attribute__((ext_vector_type(4))) float f32x4;

__device__ __forceinline__ u16 f2bf(float f) {
    uint32_t x = __float_as_uint(f);
    x += 0x7fffu + ((x >> 16) & 1u);      // round-to-nearest-even
    return (u16)(x >> 16);
}
__device__ __forceinline__ float bf2f(u16 u) {
    return __uint_as_float(((uint32_t)u) << 16);
}

// async global->LDS, 16B per lane (used by phase-1 GEMM only)
__device__ __forceinline__ void async_cp16(const u16* g, u16* l) {
    auto* g1 = (const __attribute__((address_space(1))) u16*)g;
    auto* l3 = (__attribute__((address_space(3))) u16*)(uintptr_t)l;
    __builtin_amdgcn_global_load_lds((const __attribute__((address_space(1))) void*)g1,
                                     (__attribute__((address_space(3))) void*)l3,
                                     16, 0, 0);
}

#define MFMA16(a, b, c) __builtin_amdgcn_mfma_f32_16x16x32_bf16((a), (b), (c), 0, 0, 0)

// ---------------------------------------------------------------------------
__global__ __launch_bounds__(256) void zero_kernel(float* __restrict__ p, int n) {
    int i = blockIdx.x * 256 + threadIdx.x;
    if (i < n) p[i] = 0.0f;
}

// fp32 -> bf16 pack: dst[r*cols+c] = bf16(src[r*src_ld + col0 + c])
__global__ __launch_bounds__(256) void conv_bf(
    const float* __restrict__ src, int src_ld, int col0, int cols,
    u16* __restrict__ dst, int total4)
{
    int i4 = blockIdx.x * 256 + threadIdx.x;
    if (i4 >= total4) return;
    int i = i4 * 4;
    int r = i / cols, c = i - r * cols;
    const float4 v = *(const float4*)(src + (size_t)r * src_ld + col0 + c);
    ushort4 o;
    o.x = f2bf(v.x); o.y = f2bf(v.y); o.z = f2bf(v.z); o.w = f2bf(v.w);
    *(ushort4*)(dst + i) = o;
}

// ---------------------------------------------------------------------------
// Phase 1 MFMA GEMM: C[m,n] = bf16( sum_k X[row(m),k]*W[n,k] + bias[n] )
// 128x128 tile, BK=32, 256 thr (4 waves, 2x2 of 64x64), 16x16x32 MFMA.
// ---------------------------------------------------------------------------
__global__ __launch_bounds__(256) void mfma_p1(
    const u16* __restrict__ X, int t0, int tcshift,
    const u16* __restrict__ W, const float* __restrict__ bias,
    u16* __restrict__ C)
{
    __shared__ u16 As[128 * 32];
    __shared__ u16 Bs[128 * 32];
    __shared__ int rowoff[128];
    const int tid = threadIdx.x;
    const int n0 = blockIdx.x * 128;
    const int m0 = blockIdx.y * 128;
    const int tcmask = (1 << tcshift) - 1;
    if (tid < 128) {
        int m = m0 + tid;
        rowoff[tid] = ((m >> tcshift) * T_ + t0 + (m & tcmask)) * E_;
    }
    __syncthreads();

    const int lane = tid & 63;
    const int wm = ((tid >> 6) & 1) * 64;
    const int wn = (tid >> 7) * 64;
    const int fr = lane & 15;
    const int kq = (lane >> 4) * 8;
    const int wbase = (tid & 192) * 8;

    f32x4 acc[4][4] = {};

    for (int k0 = 0; k0 < E_; k0 += 32) {
#pragma unroll
        for (int p = 0; p < 2; ++p) {
            int c = p * 256 + tid;
            int row = c >> 2, kc = (c & 3) * 8;
            async_cp16(X + rowoff[row] + k0 + kc, &As[p * 2048 + wbase]);
            async_cp16(W + (size_t)(n0 + row) * E_ + k0 + kc, &Bs[p * 2048 + wbase]);
        }
        __syncthreads();
        bf16x8 a[4], b[4];
#pragma unroll
        for (int i = 0; i < 4; ++i) {
            a[i] = *(const bf16x8*)&As[(wm + i * 16 + fr) * 32 + kq];
            b[i] = *(const bf16x8*)&Bs[(wn + i * 16 + fr) * 32 + kq];
        }
#pragma unroll
        for (int mt = 0; mt < 4; ++mt)
#pragma unroll
            for (int nt = 0; nt < 4; ++nt)
                acc[mt][nt] = MFMA16(a[mt], b[nt], acc[mt][nt]);
        __syncthreads();
    }

#pragma unroll
    for (int mt = 0; mt < 4; ++mt)
#pragma unroll
        for (int nt = 0; nt < 4; ++nt) {
            int n = n0 + wn + nt * 16 + fr;
            float bs = bias[n];
#pragma unroll
            for (int i = 0; i < 4; ++i) {
                int m = m0 + wm + mt * 16 + (lane >> 4) * 4 + i;
                C[(size_t)m * H3_ + n] = f2bf(acc[mt][nt][i] + bs);
            }
        }
}

// ---------------------------------------------------------------------------
// Fused per-step kernel, balanced 160 blocks, direct global->VGPR k-loop
// (no LDS staging, no barriers in the loop -> compiler pipelines loads).
//   bid   0..31 : spk rows (M=128), h-tile 32: pass gi (A[b,adr]@Whsi) +
//                 pass gh (A[b,spk]@Whs), both in the same k-iter.
//   bid  32..63 : adr rows, symmetric.
//   bid 64..159 : others, m-tile = 256 of 768 rows x h-tile 32, gh only.
// Each block = 50.3 MFLOP (uniform). Waves: m-half x h-half(16).
// Epilogue applies the GRU gate in registers; writes Anew fp32 + AbfNew bf16.
// ---------------------------------------------------------------------------
__global__ __launch_bounds__(256) void fused_step(
    const u16* __restrict__ AbfOld, u16* __restrict__ AbfNew,
    const float* __restrict__ Aold, float* __restrict__ Anew,
    const int* __restrict__ dig, int t, int tl, int Tc,
    const u16* __restrict__ Whsi, const u16* __restrict__ Whs,
    const u16* __restrict__ Whai, const u16* __restrict__ Wha,
    const u16* __restrict__ Who,
    const u16* __restrict__ GIX, const u16* __restrict__ GIA,
    const u16* __restrict__ GIO,
    const float* __restrict__ ws_bhh, const float* __restrict__ wa_bhh,
    const float* __restrict__ wo_bhh)
{
    __shared__ int r1off[128];
    __shared__ int r2off[256];
    __shared__ int gioff[256];
    const int tid = threadIdx.x;
    const int bid = blockIdx.x;
    const int kind = (bid < 32) ? 0 : (bid < 64 ? 1 : 2);

    int h0, mtile = 0;
    if (kind < 2) {
        h0 = (bid & 31) * 32;
    } else {
        int idx = bid - 64;
        mtile = idx >> 5;
        h0 = (idx & 31) * 32;
    }

    const u16* W1 = (kind == 0) ? Whsi : Whai;
    const u16* W2 = (kind == 0) ? Whs : (kind == 1 ? Wha : Who);
    const u16* GIpre = (kind == 0) ? GIX : (kind == 1 ? GIA : GIO);
    const float* bhh = (kind == 0) ? ws_bhh : (kind == 1 ? wa_bhh : wo_bhh);

    if (kind < 2) {
        if (tid < 128) {
            int b = tid;
            int spk = dig[(b * T_ + t) * 2 + 0];
            int adr = dig[(b * T_ + t) * 2 + 1];
            int role = (kind == 0) ? spk : adr;
            int oth  = (kind == 0) ? adr : spk;
            r1off[tid] = (b * R_ + oth) * H_;   // gi input rows
            r2off[tid] = (b * R_ + role) * H_;  // gh input rows == output rows
            gioff[tid] = (b * Tc + tl) * H3_;
        }
    } else {
        int mo = mtile * 256 + tid;
        int b = mo / 6, j = mo - b * 6;
        int spk = dig[(b * T_ + t) * 2 + 0];
        int adr = dig[(b * T_ + t) * 2 + 1];
        int cc = 0, role = 0;
        for (int r = 0; r < R_; ++r)
            if (r != spk && r != adr) { if (cc == j) { role = r; break; } ++cc; }
        r2off[tid] = (b * R_ + role) * H_;
        gioff[tid] = (b * Tc + tl) * H3_;
    }
    __syncthreads();

    const int lane = tid & 63;
    const int mh = (tid >> 6) & 1;        // wave m-half
    const int hh = tid >> 7;              // wave h-half (16 h each)
    const int fr = lane & 15;
    const int kq = (lane >> 4) * 8;
    const int h = h0 + hh * 16 + fr;      // this lane's h (for B rows & C cols)

    size_t wrow[3];
#pragma unroll
    for (int g = 0; g < 3; ++g)
        wrow[g] = (size_t)(g * H_ + h) * H_;

    if (kind < 2) {
        // ---- spk / adr: M=128, dual GEMM (gi + gh) ----
        int aoff0[4], aoff1[4];
#pragma unroll
        for (int mf = 0; mf < 4; ++mf) {
            int row = mh * 64 + mf * 16 + fr;
            aoff0[mf] = r1off[row];
            aoff1[mf] = r2off[row];
        }
        f32x4 acc[4][4] = {};   // [mf][cg]: 0=r(gi+gh), 1=z(gi+gh), 2=gi_n, 3=gh_n
        for (int k0 = 0; k0 < H_; k0 += 32) {
            bf16x8 a0[4], a1[4], b0[3], b1[3];
#pragma unroll
            for (int g = 0; g < 3; ++g) {
                b0[g] = *(const bf16x8*)(W1 + wrow[g] + k0 + kq);
                b1[g] = *(const bf16x8*)(W2 + wrow[g] + k0 + kq);
            }
#pragma unroll
            for (int mf = 0; mf < 4; ++mf) {
                a0[mf] = *(const bf16x8*)(AbfOld + aoff0[mf] + k0 + kq);
                a1[mf] = *(const bf16x8*)(AbfOld + aoff1[mf] + k0 + kq);
            }
#pragma unroll
            for (int mf = 0; mf < 4; ++mf) {
                acc[mf][0] = MFMA16(a0[mf], b0[0], acc[mf][0]);
                acc[mf][1] = MFMA16(a0[mf], b0[1], acc[mf][1]);
                acc[mf][2] = MFMA16(a0[mf], b0[2], acc[mf][2]);
                acc[mf][0] = MFMA16(a1[mf], b1[0], acc[mf][0]);
                acc[mf][1] = MFMA16(a1[mf], b1[1], acc[mf][1]);
                acc[mf][3] = MFMA16(a1[mf], b1[2], acc[mf][3]);
            }
        }
        float bh_r = bhh[h], bh_z = bhh[H_ + h], bh_n = bhh[2 * H_ + h];
#pragma unroll
        for (int mf = 0; mf < 4; ++mf) {
#pragma unroll
            for (int i = 0; i < 4; ++i) {
                int row = mh * 64 + mf * 16 + (lane >> 4) * 4 + i;
                int gio = gioff[row];
                float gi_r = bf2f(GIpre[gio + h]);
                float gi_z = bf2f(GIpre[gio + H_ + h]);
                float gi_n = bf2f(GIpre[gio + 2 * H_ + h]);
                float rg = 1.0f / (1.0f + __expf(-(gi_r + acc[mf][0][i] + bh_r)));
                float zg = 1.0f / (1.0f + __expf(-(gi_z + acc[mf][1][i] + bh_z)));
                float ng = tanhf(gi_n + acc[mf][2][i] + rg * (acc[mf][3][i] + bh_n));
                size_t o = (size_t)r2off[row] + h;
                float hold = Aold[o];
                float out = (1.0f - zg) * ng + zg * hold;
                Anew[o] = out;
                AbfNew[o] = f2bf(out);
            }
        }
    } else {
        // ---- others: M=256, single GEMM (gh); gi comes entirely from GIO ----
        int aoff[8];
#pragma unroll
        for (int mf = 0; mf < 8; ++mf)
            aoff[mf] = r2off[mh * 128 + mf * 16 + fr];
        f32x4 acc[8][3] = {};   // [mf][cg]: 0=r, 1=z, 2=gh_n
        for (int k0 = 0; k0 < H_; k0 += 32) {
            bf16x8 a[8], b[3];
#pragma unroll
            for (int g = 0; g < 3; ++g)
                b[g] = *(const bf16x8*)(W2 + wrow[g] + k0 + kq);
#pragma unroll
            for (int mf = 0; mf < 8; ++mf)
                a[mf] = *(const bf16x8*)(AbfOld + aoff[mf] + k0 + kq);
#pragma unroll
            for (int mf = 0; mf < 8; ++mf) {
                acc[mf][0] = MFMA16(a[mf], b[0], acc[mf][0]);
                acc[mf][1] = MFMA16(a[mf], b[1], acc[mf][1]);
                acc[mf][2] = MFMA16(a[mf], b[2], acc[mf][2]);
            }
        }
        float bh_r = bhh[h], bh_z = bhh[H_ + h], bh_n = bhh[2 * H_ + h];
#pragma unroll
        for (int mf = 0; mf < 8; ++mf) {
#pragma unroll
            for (int i = 0; i < 4; ++i) {
                int row = mh * 128 + mf * 16 + (lane >> 4) * 4 + i;
                int gio = gioff[row];
                float gi_r = bf2f(GIpre[gio + h]);
                float gi_z = bf2f(GIpre[gio + H_ + h]);
                float gi_n = bf2f(GIpre[gio + 2 * H_ + h]);
                float rg = 1.0f / (1.0f + __expf(-(gi_r + acc[mf][0][i] + bh_r)));
                float zg = 1.0f / (1.0f + __expf(-(gi_z + acc[mf][1][i] + bh_z)));
                float ng = tanhf(gi_n + rg * (acc[mf][2][i] + bh_n));
                size_t o = (size_t)r2off[row] + h;
                float hold = Aold[o];
                float out = (1.0f - zg) * ng + zg * hold;
                Anew[o] = out;
                AbfNew[o] = f2bf(out);
            }
        }
    }
}

// ---------------------------------------------------------------------------
extern "C" void kernel_launch(void* const* d_in, const int* in_sizes, int n_in,
                              void* d_out, int out_size, void* d_ws, size_t ws_size,
                              hipStream_t stream) {
    const float* enc    = (const float*)d_in[0];
    const int*   dig    = (const int*)d_in[1];
    const float* ws_ih  = (const float*)d_in[2];
    const float* ws_hh  = (const float*)d_in[3];
    const float* ws_bih = (const float*)d_in[4];
    const float* ws_bhh = (const float*)d_in[5];
    const float* wa_ih  = (const float*)d_in[6];
    const float* wa_hh  = (const float*)d_in[7];
    const float* wa_bih = (const float*)d_in[8];
    const float* wa_bhh = (const float*)d_in[9];
    const float* wo_ih  = (const float*)d_in[10];
    const float* wo_hh  = (const float*)d_in[11];
    const float* wo_bih = (const float*)d_in[12];
    const float* wo_bhh = (const float*)d_in[13];

    float* A0 = (float*)d_out;                    // (B, R, H) final output

    // ---- workspace layout (bytes) ----
    char* p = (char*)d_ws;
    auto take = [&](size_t bytes) { char* q = p; p += (bytes + 255) & ~(size_t)255; return q; };
    u16*   enc_bf = (u16*)  take((size_t)B_ * T_ * E_ * 2);          // 33.6 MB
    u16*   W1s    = (u16*)  take((size_t)H3_ * E_ * 2);              // 12.6 MB
    u16*   W1a    = (u16*)  take((size_t)H3_ * E_ * 2);
    u16*   W1o    = (u16*)  take((size_t)H3_ * E_ * 2);
    u16*   Whsi   = (u16*)  take((size_t)H3_ * H_ * 2);              // 6.3 MB
    u16*   Whai   = (u16*)  take((size_t)H3_ * H_ * 2);
    u16*   Whs    = (u16*)  take((size_t)H3_ * H_ * 2);
    u16*   Wha    = (u16*)  take((size_t)H3_ * H_ * 2);
    u16*   Who    = (u16*)  take((size_t)H3_ * H_ * 2);
    u16*   Abf0   = (u16*)  take((size_t)B_ * R_ * H_ * 2);          // 2 MB
    u16*   Abf1   = (u16*)  take((size_t)B_ * R_ * H_ * 2);          // 2 MB
    float* A1     = (float*)take((size_t)B_ * R_ * H_ * 4);          // 4 MB
    size_t fixed = (size_t)(p - (char*)d_ws);

    // chunk size: largest power-of-two Tc <= 64 fitting GI (3 sets, bf16)
    const size_t per_t = (size_t)3 * B_ * H3_ * 2;                   // 2.36 MB/step
    int Tc = 64;
    while (Tc > 1 && fixed + per_t * (size_t)Tc > ws_size) Tc >>= 1;
    int tcshift = 0;
    while ((1 << tcshift) < Tc) ++tcshift;
    const size_t GI_elems = (size_t)B_ * Tc * H3_;
    u16* GIX = (u16*)take(GI_elems * 2);
    u16* GIA = (u16*)take(GI_elems * 2);
    u16* GIO = (u16*)take(GI_elems * 2);

    dim3 blk(256);
    const size_t A_sz = (size_t)B_ * R_ * H_;

    // zero fp32 state (d_out) and bf16 state copy
    zero_kernel<<<dim3((int)((A_sz + 255) / 256)), blk, 0, stream>>>(A0, (int)A_sz);
    zero_kernel<<<dim3((int)((A_sz / 2 + 255) / 256)), blk, 0, stream>>>((float*)Abf0, (int)(A_sz / 2));

    // ---- one-time bf16 conversions ----
    {
        int t4;
        t4 = B_ * T_ * E_ / 4;
        conv_bf<<<dim3((t4 + 255) / 256), blk, 0, stream>>>(enc, E_, 0, E_, enc_bf, t4);
        t4 = H3_ * E_ / 4;
        conv_bf<<<dim3((t4 + 255) / 256), blk, 0, stream>>>(ws_ih, E_ + H_, 0, E_, W1s, t4);
        conv_bf<<<dim3((t4 + 255) / 256), blk, 0, stream>>>(wa_ih, E_ + H_, 0, E_, W1a, t4);
        conv_bf<<<dim3((t4 + 255) / 256), blk, 0, stream>>>(wo_ih, E_, 0, E_, W1o, t4);
        t4 = H3_ * H_ / 4;
        conv_bf<<<dim3((t4 + 255) / 256), blk, 0, stream>>>(ws_ih, E_ + H_, E_, H_, Whsi, t4);
        conv_bf<<<dim3((t4 + 255) / 256), blk, 0, stream>>>(wa_ih, E_ + H_, E_, H_, Whai, t4);
        conv_bf<<<dim3((t4 + 255) / 256), blk, 0, stream>>>(ws_hh, H_, 0, H_, Whs, t4);
        conv_bf<<<dim3((t4 + 255) / 256), blk, 0, stream>>>(wa_hh, H_, 0, H_, Wha, t4);
        conv_bf<<<dim3((t4 + 255) / 256), blk, 0, stream>>>(wo_hh, H_, 0, H_, Who, t4);
    }

    float* Acur = A0;   // fp32 master state (read)
    float* Anxt = A1;
    u16*   Bcur = Abf0; // bf16 state (read)
    u16*   Bnxt = Abf1;
    for (int t0 = 0; t0 < T_; t0 += Tc) {
        // Phase 1 (chunk): input-side gate contributions, bf16 MFMA.
        dim3 g1(H3_ / 128, (B_ * Tc) / 128);
        mfma_p1<<<g1, blk, 0, stream>>>(enc_bf, t0, tcshift, W1s, ws_bih, GIX);
        mfma_p1<<<g1, blk, 0, stream>>>(enc_bf, t0, tcshift, W1a, wa_bih, GIA);
        mfma_p1<<<g1, blk, 0, stream>>>(enc_bf, t0, tcshift, W1o, wo_bih, GIO);

        // Phase 2: one fused dispatch per timestep (160 balanced blocks).
        for (int t = t0; t < t0 + Tc; ++t) {
            fused_step<<<dim3(160), blk, 0, stream>>>(
                Bcur, Bnxt, Acur, Anxt, dig, t, t - t0, Tc,
                Whsi, Whs, Whai, Wha, Who, GIX, GIA, GIO,
                ws_bhh, wa_bhh, wo_bhh);
            float* tf = Acur; Acur = Anxt; Anxt = tf;
            u16*   tb = Bcur; Bcur = Bnxt; Bnxt = tb;
        }
    }
    // 64 steps (even number of swaps): final fp32 state is in A0 == d_out.
}